// Round 1
// baseline (491.642 us; speedup 1.0000x reference)
//
#include <hip/hip_runtime.h>
#include <hip/hip_bf16.h>

typedef __attribute__((ext_vector_type(8))) short bf16x8;
typedef __attribute__((ext_vector_type(4))) float f32x4;

typedef const __attribute__((address_space(1))) void gv_t;
typedef __attribute__((address_space(3))) void lv_t;
#define GLL16(g, l) __builtin_amdgcn_global_load_lds((gv_t*)(g), (lv_t*)(l), 16, 0, 0)

__device__ __forceinline__ short f2bf(float f) {
    __hip_bfloat16 h = __float2bfloat16(f);
    return *reinterpret_cast<short*>(&h);
}

__device__ __forceinline__ float wred(float v) {
    #pragma unroll
    for (int m = 1; m < 64; m <<= 1) v += __shfl_xor(v, m);
    return v;
}

// ---------------- fp32 -> bf16 convert (weights) ----------------
__global__ __launch_bounds__(256) void cvt_kernel(const float* __restrict__ in,
                                                  short* __restrict__ out, int n4) {
    int i = blockIdx.x * 256 + threadIdx.x;
    if (i < n4) {
        float4 v = ((const float4*)in)[i];
        short4 o;
        o.x = f2bf(v.x); o.y = f2bf(v.y); o.z = f2bf(v.z); o.w = f2bf(v.w);
        ((short4*)out)[i] = o;
    }
}

// ---------------- LayerNorm (fp32 in, bf16 out), row = 1024 ----------------
__global__ __launch_bounds__(256) void ln_kernel(const float* __restrict__ x,
                                                 const float* __restrict__ g,
                                                 short* __restrict__ y) {
    const int row = blockIdx.x, tid = threadIdx.x;
    const float4 v = ((const float4*)(x + (size_t)row * 1024))[tid];
    float s = v.x + v.y + v.z + v.w;
    float s2 = v.x * v.x + v.y * v.y + v.z * v.z + v.w * v.w;
    #pragma unroll
    for (int m = 1; m < 64; m <<= 1) { s += __shfl_xor(s, m); s2 += __shfl_xor(s2, m); }
    __shared__ float rs[4], rs2[4];
    if ((tid & 63) == 0) { rs[tid >> 6] = s; rs2[tid >> 6] = s2; }
    __syncthreads();
    s = rs[0] + rs[1] + rs[2] + rs[3];
    s2 = rs2[0] + rs2[1] + rs2[2] + rs2[3];
    const float mean = s * (1.0f / 1024.0f);
    const float var = s2 * (1.0f / 1024.0f) - mean * mean;
    const float r = rsqrtf(var + 1e-5f);
    const float4 gg = ((const float4*)g)[tid];
    short4 o;
    o.x = f2bf((v.x - mean) * r * gg.x);
    o.y = f2bf((v.y - mean) * r * gg.y);
    o.z = f2bf((v.z - mean) * r * gg.z);
    o.w = f2bf((v.w - mean) * r * gg.w);
    ((short4*)y)[(size_t)row * 256 + tid] = o;
}

// ---------------- GEMM: C[M,N] = A[M,K] * B[N,K]^T, bf16 in, templated epilogue ----
// EPI 0: QKV split -> q[b,h,t,d], k[b,h,t,d], vT[b,h,d,t]  (bf16)
// EPI 1: fp32 row-major
// EPI 2: exact GELU -> bf16 row-major
template <int EPI>
__global__ __launch_bounds__(256, 2) void gemm_bt(const short* __restrict__ A,
                                                  const short* __restrict__ Bw,
                                                  int M, int N, int K,
                                                  void* __restrict__ o0,
                                                  void* __restrict__ o1,
                                                  void* __restrict__ o2) {
    __shared__ __align__(16) short As[128 * 32];
    __shared__ __align__(16) short Bs[128 * 32];
    const int tid = threadIdx.x;
    const int wid = tid >> 6, lane = tid & 63;
    const int wm = wid >> 1, wn = wid & 1;
    const int col = lane & 15, grp = lane >> 4;
    const int m0 = blockIdx.x * 128, n0 = blockIdx.y * 128;
    f32x4 acc[4][4] = {};
    const int rowA = tid >> 2;
    const int kc = (tid & 3) * 8;
    const short* ga = A + (size_t)(m0 + rowA) * K + kc;
    const short* gb = Bw + (size_t)(n0 + rowA) * K + kc;
    short* lA = As + wid * 512;
    short* lB = Bs + wid * 512;
    for (int k0 = 0; k0 < K; k0 += 32) {
        GLL16(ga + k0, lA);
        GLL16(ga + k0 + (size_t)64 * K, lA + 2048);
        GLL16(gb + k0, lB);
        GLL16(gb + k0 + (size_t)64 * K, lB + 2048);
        __syncthreads();
        bf16x8 af[4], bfr[4];
        #pragma unroll
        for (int i = 0; i < 4; ++i) {
            af[i] = *(const bf16x8*)&As[(wm * 64 + i * 16 + col) * 32 + grp * 8];
            bfr[i] = *(const bf16x8*)&Bs[(wn * 64 + i * 16 + col) * 32 + grp * 8];
        }
        #pragma unroll
        for (int mi = 0; mi < 4; ++mi)
            #pragma unroll
            for (int ni = 0; ni < 4; ++ni)
                acc[mi][ni] = __builtin_amdgcn_mfma_f32_16x16x32_bf16(af[mi], bfr[ni], acc[mi][ni], 0, 0, 0);
        __syncthreads();
    }
    #pragma unroll
    for (int mi = 0; mi < 4; ++mi) {
        #pragma unroll
        for (int ni = 0; ni < 4; ++ni) {
            #pragma unroll
            for (int i = 0; i < 4; ++i) {
                const int m = m0 + wm * 64 + mi * 16 + grp * 4 + i;
                const int n = n0 + wn * 64 + ni * 16 + col;
                const float v = acc[mi][ni][i];
                if (EPI == 0) {
                    const int b = m >> 11, t = m & 2047;
                    const int which = n >> 10, nn = n & 1023;
                    const int h = nn >> 6, d = nn & 63;
                    const size_t bh = (size_t)(b * 16 + h);
                    if (which == 0)
                        ((short*)o0)[(bh * 2048 + t) * 64 + d] = f2bf(v);
                    else if (which == 1)
                        ((short*)o1)[(bh * 2048 + t) * 64 + d] = f2bf(v);
                    else
                        ((short*)o2)[(bh * 64 + d) * 2048 + t] = f2bf(v);
                } else if (EPI == 1) {
                    ((float*)o0)[(size_t)m * N + n] = v;
                } else {
                    const float gl = 0.5f * v * (1.0f + erff(v * 0.70710678118654752f));
                    ((short*)o0)[(size_t)m * N + n] = f2bf(gl);
                }
            }
        }
    }
}

// ---------------- Flash attention, causal. Q,K:[b,h,t,d] VT:[b,h,d,t] bf16 ----------
__global__ __launch_bounds__(256) void attn_kernel(const short* __restrict__ Q,
                                                   const short* __restrict__ Kg,
                                                   const short* __restrict__ VT,
                                                   short* __restrict__ Y) {
    __shared__ __align__(16) short Plds[4][16 * 72];
    const int qt = blockIdx.x, bh = blockIdx.y;
    const int tid = threadIdx.x, wid = tid >> 6, lane = tid & 63;
    const int col = lane & 15, grp = lane >> 4;
    const int q0 = qt * 64 + wid * 16;
    const short* Qb = Q + (size_t)bh * 2048 * 64;
    const short* Kb = Kg + (size_t)bh * 2048 * 64;
    const short* Vb = VT + (size_t)bh * 64 * 2048;
    short* Pw = &Plds[wid][0];
    bf16x8 qa[2];
    #pragma unroll
    for (int kf = 0; kf < 2; ++kf)
        qa[kf] = *(const bf16x8*)&Qb[(size_t)(q0 + col) * 64 + kf * 32 + grp * 8];
    f32x4 o[4] = {};
    float mrow[4] = {-1e30f, -1e30f, -1e30f, -1e30f};
    float lrow[4] = {0.f, 0.f, 0.f, 0.f};
    for (int kt = 0; kt <= qt; ++kt) {
        const int kbase = kt * 64;
        f32x4 s[4];
        #pragma unroll
        for (int nf = 0; nf < 4; ++nf) {
            bf16x8 kb0 = *(const bf16x8*)&Kb[(size_t)(kbase + nf * 16 + col) * 64 + grp * 8];
            bf16x8 kb1 = *(const bf16x8*)&Kb[(size_t)(kbase + nf * 16 + col) * 64 + 32 + grp * 8];
            f32x4 z = {0.f, 0.f, 0.f, 0.f};
            z = __builtin_amdgcn_mfma_f32_16x16x32_bf16(qa[0], kb0, z, 0, 0, 0);
            z = __builtin_amdgcn_mfma_f32_16x16x32_bf16(qa[1], kb1, z, 0, 0, 0);
            #pragma unroll
            for (int i = 0; i < 4; ++i) s[nf][i] = z[i] * 0.125f;
        }
        if (kt == qt) {
            #pragma unroll
            for (int nf = 0; nf < 4; ++nf)
                #pragma unroll
                for (int i = 0; i < 4; ++i)
                    if (nf * 16 + col > wid * 16 + grp * 4 + i) s[nf][i] = -1e30f;
        }
        #pragma unroll
        for (int i = 0; i < 4; ++i) {
            float mx = fmaxf(fmaxf(s[0][i], s[1][i]), fmaxf(s[2][i], s[3][i]));
            #pragma unroll
            for (int d = 1; d < 16; d <<= 1) mx = fmaxf(mx, __shfl_xor(mx, d));
            const float mnew = fmaxf(mrow[i], mx);
            const float sc = __expf(mrow[i] - mnew);
            mrow[i] = mnew;
            float p0 = __expf(s[0][i] - mnew);
            float p1 = __expf(s[1][i] - mnew);
            float p2 = __expf(s[2][i] - mnew);
            float p3 = __expf(s[3][i] - mnew);
            float rsum = p0 + p1 + p2 + p3;
            #pragma unroll
            for (int d = 1; d < 16; d <<= 1) rsum += __shfl_xor(rsum, d);
            lrow[i] = lrow[i] * sc + rsum;
            #pragma unroll
            for (int nf = 0; nf < 4; ++nf) o[nf][i] *= sc;
            const int pr = (grp * 4 + i) * 72;
            Pw[pr + 0 * 16 + col] = f2bf(p0);
            Pw[pr + 1 * 16 + col] = f2bf(p1);
            Pw[pr + 2 * 16 + col] = f2bf(p2);
            Pw[pr + 3 * 16 + col] = f2bf(p3);
        }
        const bf16x8 pa0 = *(const bf16x8*)&Pw[col * 72 + grp * 8];
        const bf16x8 pa1 = *(const bf16x8*)&Pw[col * 72 + 32 + grp * 8];
        #pragma unroll
        for (int nf = 0; nf < 4; ++nf) {
            bf16x8 vb0 = *(const bf16x8*)&Vb[(size_t)(nf * 16 + col) * 2048 + kbase + grp * 8];
            bf16x8 vb1 = *(const bf16x8*)&Vb[(size_t)(nf * 16 + col) * 2048 + kbase + 32 + grp * 8];
            o[nf] = __builtin_amdgcn_mfma_f32_16x16x32_bf16(pa0, vb0, o[nf], 0, 0, 0);
            o[nf] = __builtin_amdgcn_mfma_f32_16x16x32_bf16(pa1, vb1, o[nf], 0, 0, 0);
        }
    }
    const int b = bh >> 4, h = bh & 15;
    #pragma unroll
    for (int nf = 0; nf < 4; ++nf)
        #pragma unroll
        for (int i = 0; i < 4; ++i) {
            const int t = qt * 64 + wid * 16 + grp * 4 + i;
            const int c = h * 64 + nf * 16 + col;
            Y[((size_t)b * 2048 + t) * 1024 + c] = f2bf(o[nf][i] / lrow[i]);
        }
}

// ---------------- Hyperbolic residual: out = expmap(x, v, c), per-head wave ------
__global__ __launch_bounds__(256) void expmap_kernel(const float* __restrict__ x,
                                                     const float* __restrict__ v,
                                                     const float* __restrict__ carr,
                                                     float* __restrict__ out) {
    const int blk = blockIdx.x;
    const int row = blk >> 2;
    const int head = (blk & 3) * 4 + (threadIdx.x >> 6);
    const int lane = threadIdx.x & 63;
    const size_t idx = (size_t)row * 1024 + head * 64 + lane;
    float c = carr[head];
    c = fminf(fmaxf(c, 1e-4f), 1.0f);
    const float xe = x[idx], ve = v[idx];
    const float xn = wred(xe * xe);
    const float vns = wred(ve * ve);
    const float vn = sqrtf(vns + 1e-9f);
    const float sf = 2.0f / (1.0f + c * xn + 1e-9f);
    const float targ = fabsf(0.5f * c * sf * vns);
    const float coeff = (1.0f / (sqrtf(c + 1e-9f) + 1e-9f)) * tanhf(sqrtf(targ + 1e-9f));
    const float ye = coeff * ve / (vn + 1e-9f);
    const float yn = wred(ye * ye);
    const float ip = wred(xe * ye);
    const float num = (1.0f + 2.0f * c * ip + c * yn) * xe + (1.0f - c * xn) * ye;
    const float den = 1.0f + 2.0f * c * ip + c * c * xn * yn;
    out[idx] = num / (den + 1e-9f);
}

extern "C" void kernel_launch(void* const* d_in, const int* in_sizes, int n_in,
                              void* d_out, int out_size, void* d_ws, size_t ws_size,
                              hipStream_t stream) {
    (void)in_sizes; (void)n_in; (void)out_size; (void)ws_size;
    const float* x      = (const float*)d_in[0];
    const float* ln1_g  = (const float*)d_in[1];
    const float* w_qkv  = (const float*)d_in[2];
    const float* w_proj = (const float*)d_in[3];
    const float* c_attn = (const float*)d_in[4];
    const float* ln2_g  = (const float*)d_in[5];
    const float* w_fc   = (const float*)d_in[6];
    const float* w_mlp  = (const float*)d_in[7];
    const float* c_mlp  = (const float*)d_in[8];
    float* out = (float*)d_out;
    char* ws = (char*)d_ws;
    const size_t MB = 1024 * 1024;

    short* wqkv_bf  = (short*)(ws + 0 * MB);    // 6 MB
    short* wproj_bf = (short*)(ws + 6 * MB);    // 2 MB
    short* wfc_bf   = (short*)(ws + 8 * MB);    // 8 MB
    short* wmlp_bf  = (short*)(ws + 16 * MB);   // 8 MB
    short* y_bf     = (short*)(ws + 24 * MB);   // 8 MB (LN1 out; reused for LN2 out)
    short* q_bf     = (short*)(ws + 32 * MB);   // 8 MB
    short* k_bf     = (short*)(ws + 40 * MB);   // 8 MB
    short* vT_bf    = (short*)(ws + 48 * MB);   // 8 MB
    short* att_bf   = (short*)(ws + 56 * MB);   // 8 MB
    float* a_f32    = (float*)(ws + 64 * MB);   // 16 MB
    float* x1       = (float*)(ws + 80 * MB);   // 16 MB
    short* g_bf     = (short*)(ws + 32 * MB);   // 32 MB (reuses q/k/vT/att)
    float* h_f32    = (float*)(ws + 64 * MB);   // 16 MB (reuses a)

    cvt_kernel<<<3072, 256, 0, stream>>>(w_qkv, wqkv_bf, 3072 * 1024 / 4);
    cvt_kernel<<<1024, 256, 0, stream>>>(w_proj, wproj_bf, 1024 * 1024 / 4);
    cvt_kernel<<<4096, 256, 0, stream>>>(w_fc, wfc_bf, 4096 * 1024 / 4);
    cvt_kernel<<<4096, 256, 0, stream>>>(w_mlp, wmlp_bf, 1024 * 4096 / 4);

    ln_kernel<<<4096, 256, 0, stream>>>(x, ln1_g, y_bf);
    gemm_bt<0><<<dim3(32, 24), 256, 0, stream>>>(y_bf, wqkv_bf, 4096, 3072, 1024,
                                                 q_bf, k_bf, vT_bf);
    attn_kernel<<<dim3(32, 32), 256, 0, stream>>>(q_bf, k_bf, vT_bf, att_bf);
    gemm_bt<1><<<dim3(32, 8), 256, 0, stream>>>(att_bf, wproj_bf, 4096, 1024, 1024,
                                                a_f32, nullptr, nullptr);
    expmap_kernel<<<16384, 256, 0, stream>>>(x, a_f32, c_attn, x1);
    ln_kernel<<<4096, 256, 0, stream>>>(x1, ln2_g, y_bf);
    gemm_bt<2><<<dim3(32, 32), 256, 0, stream>>>(y_bf, wfc_bf, 4096, 4096, 1024,
                                                 g_bf, nullptr, nullptr);
    gemm_bt<1><<<dim3(32, 8), 256, 0, stream>>>(g_bf, wmlp_bf, 4096, 1024, 4096,
                                                h_f32, nullptr, nullptr);
    expmap_kernel<<<16384, 256, 0, stream>>>(x1, h_f32, c_mlp, out);
}

// Round 2
// 420.144 us; speedup vs baseline: 1.1702x; 1.1702x over previous
//
#include <hip/hip_runtime.h>
#include <hip/hip_bf16.h>

typedef __attribute__((ext_vector_type(8))) short bf16x8;
typedef __attribute__((ext_vector_type(4))) float f32x4;

typedef const __attribute__((address_space(1))) void gv_t;
typedef __attribute__((address_space(3))) void lv_t;
#define GLL16(g, l) __builtin_amdgcn_global_load_lds((gv_t*)(g), (lv_t*)(l), 16, 0, 0)

__device__ __forceinline__ short f2bf(float f) {
    __hip_bfloat16 h = __float2bfloat16(f);
    return *reinterpret_cast<short*>(&h);
}

__device__ __forceinline__ float wred(float v) {
    #pragma unroll
    for (int m = 1; m < 64; m <<= 1) v += __shfl_xor(v, m);
    return v;
}

// ---------------- fp32 -> bf16 convert (weights) ----------------
__global__ __launch_bounds__(256) void cvt_kernel(const float* __restrict__ in,
                                                  short* __restrict__ out, int n4) {
    int i = blockIdx.x * 256 + threadIdx.x;
    if (i < n4) {
        float4 v = ((const float4*)in)[i];
        short4 o;
        o.x = f2bf(v.x); o.y = f2bf(v.y); o.z = f2bf(v.z); o.w = f2bf(v.w);
        ((short4*)out)[i] = o;
    }
}

// ---------------- LayerNorm (fp32 in, bf16 out), row = 1024 ----------------
__global__ __launch_bounds__(256) void ln_kernel(const float* __restrict__ x,
                                                 const float* __restrict__ g,
                                                 short* __restrict__ y) {
    const int row = blockIdx.x, tid = threadIdx.x;
    const float4 v = ((const float4*)(x + (size_t)row * 1024))[tid];
    float s = v.x + v.y + v.z + v.w;
    float s2 = v.x * v.x + v.y * v.y + v.z * v.z + v.w * v.w;
    #pragma unroll
    for (int m = 1; m < 64; m <<= 1) { s += __shfl_xor(s, m); s2 += __shfl_xor(s2, m); }
    __shared__ float rs[4], rs2[4];
    if ((tid & 63) == 0) { rs[tid >> 6] = s; rs2[tid >> 6] = s2; }
    __syncthreads();
    s = rs[0] + rs[1] + rs[2] + rs[3];
    s2 = rs2[0] + rs2[1] + rs2[2] + rs2[3];
    const float mean = s * (1.0f / 1024.0f);
    const float var = s2 * (1.0f / 1024.0f) - mean * mean;
    const float r = rsqrtf(var + 1e-5f);
    const float4 gg = ((const float4*)g)[tid];
    short4 o;
    o.x = f2bf((v.x - mean) * r * gg.x);
    o.y = f2bf((v.y - mean) * r * gg.y);
    o.z = f2bf((v.z - mean) * r * gg.z);
    o.w = f2bf((v.w - mean) * r * gg.w);
    ((short4*)y)[(size_t)row * 256 + tid] = o;
}

// ---------------- GEMM: C[M,N] = A[M,K] * B[N,K]^T, bf16 in, templated epilogue ----
// EPI 0: QKV split -> q[b,h,t,d] (pre-scaled by 1/8), k[b,h,t,d], vT[b,h,d,t] (bf16)
// EPI 1: fp32 row-major
// EPI 2: exact GELU -> bf16 row-major
template <int EPI>
__global__ __launch_bounds__(256, 2) void gemm_bt(const short* __restrict__ A,
                                                  const short* __restrict__ Bw,
                                                  int M, int N, int K,
                                                  void* __restrict__ o0,
                                                  void* __restrict__ o1,
                                                  void* __restrict__ o2) {
    __shared__ __align__(16) short As[128 * 32];
    __shared__ __align__(16) short Bs[128 * 32];
    const int tid = threadIdx.x;
    const int wid = tid >> 6, lane = tid & 63;
    const int wm = wid >> 1, wn = wid & 1;
    const int col = lane & 15, grp = lane >> 4;
    const int m0 = blockIdx.x * 128, n0 = blockIdx.y * 128;
    f32x4 acc[4][4] = {};
    const int rowA = tid >> 2;
    const int kc = (tid & 3) * 8;
    const short* ga = A + (size_t)(m0 + rowA) * K + kc;
    const short* gb = Bw + (size_t)(n0 + rowA) * K + kc;
    short* lA = As + wid * 512;
    short* lB = Bs + wid * 512;
    for (int k0 = 0; k0 < K; k0 += 32) {
        GLL16(ga + k0, lA);
        GLL16(ga + k0 + (size_t)64 * K, lA + 2048);
        GLL16(gb + k0, lB);
        GLL16(gb + k0 + (size_t)64 * K, lB + 2048);
        __syncthreads();
        bf16x8 af[4], bfr[4];
        #pragma unroll
        for (int i = 0; i < 4; ++i) {
            af[i] = *(const bf16x8*)&As[(wm * 64 + i * 16 + col) * 32 + grp * 8];
            bfr[i] = *(const bf16x8*)&Bs[(wn * 64 + i * 16 + col) * 32 + grp * 8];
        }
        #pragma unroll
        for (int mi = 0; mi < 4; ++mi)
            #pragma unroll
            for (int ni = 0; ni < 4; ++ni)
                acc[mi][ni] = __builtin_amdgcn_mfma_f32_16x16x32_bf16(af[mi], bfr[ni], acc[mi][ni], 0, 0, 0);
        __syncthreads();
    }
    #pragma unroll
    for (int mi = 0; mi < 4; ++mi) {
        #pragma unroll
        for (int ni = 0; ni < 4; ++ni) {
            #pragma unroll
            for (int i = 0; i < 4; ++i) {
                const int m = m0 + wm * 64 + mi * 16 + grp * 4 + i;
                const int n = n0 + wn * 64 + ni * 16 + col;
                const float v = acc[mi][ni][i];
                if (EPI == 0) {
                    const int b = m >> 11, t = m & 2047;
                    const int which = n >> 10, nn = n & 1023;
                    const int h = nn >> 6, d = nn & 63;
                    const size_t bh = (size_t)(b * 16 + h);
                    if (which == 0)
                        ((short*)o0)[(bh * 2048 + t) * 64 + d] = f2bf(v * 0.125f);
                    else if (which == 1)
                        ((short*)o1)[(bh * 2048 + t) * 64 + d] = f2bf(v);
                    else
                        ((short*)o2)[(bh * 64 + d) * 2048 + t] = f2bf(v);
                } else if (EPI == 1) {
                    ((float*)o0)[(size_t)m * N + n] = v;
                } else {
                    const float gl = 0.5f * v * (1.0f + erff(v * 0.70710678118654752f));
                    ((short*)o0)[(size_t)m * N + n] = f2bf(gl);
                }
            }
        }
    }
}

// ---------------- Flash attention, causal, swapped-QK + k-split --------------------
// Q (pre-scaled),K:[b,h,t,d]  VT:[b,h,d,t]  bf16.  One block = 16 q-rows; 4 waves
// split the k-tiles (64 wide) round-robin, partials combined via LDS.
__global__ __launch_bounds__(256, 4) void attn_kernel(const short* __restrict__ Q,
                                                      const short* __restrict__ Kg,
                                                      const short* __restrict__ VT,
                                                      short* __restrict__ Y) {
    __shared__ float mLds[4][16], lLds[4][16];
    __shared__ float OLds[4][16][68];
    __shared__ __align__(16) short Plds[4][16 * 72];
    const int j = 127 - blockIdx.x;   // q-strip, biggest workload first
    const int bh = blockIdx.y;
    const int tid = threadIdx.x, wid = tid >> 6, lane = tid & 63;
    const int ql = lane & 15, g = lane >> 4;
    const int q0 = j * 16;
    const int lt = j >> 2;            // last k-tile index (diagonal)
    const short* Qb = Q + (size_t)bh * 2048 * 64;
    const short* Kb = Kg + (size_t)bh * 2048 * 64;
    const short* Vb = VT + (size_t)bh * 64 * 2048;
    short* Pw = &Plds[wid][0];
    bf16x8 qf[2];
    qf[0] = *(const bf16x8*)&Qb[(size_t)(q0 + ql) * 64 + 8 * g];
    qf[1] = *(const bf16x8*)&Qb[(size_t)(q0 + ql) * 64 + 32 + 8 * g];
    f32x4 o[4] = {};
    float m = -1e30f, lsum = 0.0f;
    for (int kt = wid; kt <= lt; kt += 4) {
        const int kbase = kt * 64;
        // S^T[k][q] = K_tile * Q^T : lane holds 16 k-scores of q-row ql
        f32x4 s[4];
        #pragma unroll
        for (int kb = 0; kb < 4; ++kb) {
            bf16x8 k0 = *(const bf16x8*)&Kb[(size_t)(kbase + 16 * kb + ql) * 64 + 8 * g];
            bf16x8 k1 = *(const bf16x8*)&Kb[(size_t)(kbase + 16 * kb + ql) * 64 + 32 + 8 * g];
            f32x4 z = {0.f, 0.f, 0.f, 0.f};
            z = __builtin_amdgcn_mfma_f32_16x16x32_bf16(k0, qf[0], z, 0, 0, 0);
            z = __builtin_amdgcn_mfma_f32_16x16x32_bf16(k1, qf[1], z, 0, 0, 0);
            s[kb] = z;
        }
        if (kt == lt) {  // causal mask on the diagonal tile
            #pragma unroll
            for (int kb = 0; kb < 4; ++kb)
                #pragma unroll
                for (int r = 0; r < 4; ++r)
                    if (kbase + 16 * kb + 4 * g + r > q0 + ql) s[kb][r] = -1e30f;
        }
        // row max: in-register tree + 2 shfl
        float t0 = fmaxf(fmaxf(s[0][0], s[0][1]), fmaxf(s[0][2], s[0][3]));
        float t1 = fmaxf(fmaxf(s[1][0], s[1][1]), fmaxf(s[1][2], s[1][3]));
        float t2 = fmaxf(fmaxf(s[2][0], s[2][1]), fmaxf(s[2][2], s[2][3]));
        float t3 = fmaxf(fmaxf(s[3][0], s[3][1]), fmaxf(s[3][2], s[3][3]));
        float tmax = fmaxf(fmaxf(t0, t1), fmaxf(t2, t3));
        tmax = fmaxf(tmax, __shfl_xor(tmax, 16));
        tmax = fmaxf(tmax, __shfl_xor(tmax, 32));
        const float mnew = fmaxf(m, tmax);
        const float sc = __expf(m - mnew);
        m = mnew;
        float rsum = 0.0f;
        #pragma unroll
        for (int kb = 0; kb < 4; ++kb) {
            const float e0 = __expf(s[kb][0] - mnew);
            const float e1 = __expf(s[kb][1] - mnew);
            const float e2 = __expf(s[kb][2] - mnew);
            const float e3 = __expf(s[kb][3] - mnew);
            rsum += (e0 + e1) + (e2 + e3);
            short4 pk;
            pk.x = f2bf(e0); pk.y = f2bf(e1); pk.z = f2bf(e2); pk.w = f2bf(e3);
            *(short4*)&Pw[ql * 72 + 16 * kb + 4 * g] = pk;
        }
        rsum += __shfl_xor(rsum, 16);
        rsum += __shfl_xor(rsum, 32);
        lsum = lsum * sc + rsum;
        float scr[4];
        #pragma unroll
        for (int r = 0; r < 4; ++r) scr[r] = __shfl(sc, 4 * g + r);
        #pragma unroll
        for (int nf = 0; nf < 4; ++nf)
            #pragma unroll
            for (int r = 0; r < 4; ++r) o[nf][r] *= scr[r];
        // PV: O[q][d] += P[q][k] * V[k][d]
        const bf16x8 pa0 = *(const bf16x8*)&Pw[ql * 72 + 8 * g];
        const bf16x8 pa1 = *(const bf16x8*)&Pw[ql * 72 + 32 + 8 * g];
        #pragma unroll
        for (int nf = 0; nf < 4; ++nf) {
            bf16x8 v0 = *(const bf16x8*)&Vb[(size_t)(nf * 16 + ql) * 2048 + kbase + 8 * g];
            bf16x8 v1 = *(const bf16x8*)&Vb[(size_t)(nf * 16 + ql) * 2048 + kbase + 32 + 8 * g];
            o[nf] = __builtin_amdgcn_mfma_f32_16x16x32_bf16(pa0, v0, o[nf], 0, 0, 0);
            o[nf] = __builtin_amdgcn_mfma_f32_16x16x32_bf16(pa1, v1, o[nf], 0, 0, 0);
        }
    }
    // publish partials
    if (g == 0) { mLds[wid][ql] = m; lLds[wid][ql] = lsum; }
    #pragma unroll
    for (int nf = 0; nf < 4; ++nf)
        #pragma unroll
        for (int r = 0; r < 4; ++r)
            OLds[wid][4 * g + r][nf * 16 + ql] = o[nf][r];
    __syncthreads();
    // combine across the 4 k-split partials; wave `wid` handles d-block nf=wid
    const int b = bh >> 4, h = bh & 15;
    #pragma unroll
    for (int r = 0; r < 4; ++r) {
        const int q = 4 * g + r;
        const float m0 = mLds[0][q], m1 = mLds[1][q], m2 = mLds[2][q], m3 = mLds[3][q];
        const float M = fmaxf(fmaxf(m0, m1), fmaxf(m2, m3));
        const float e0 = __expf(m0 - M), e1 = __expf(m1 - M);
        const float e2 = __expf(m2 - M), e3 = __expf(m3 - M);
        const float L = lLds[0][q] * e0 + lLds[1][q] * e1 + lLds[2][q] * e2 + lLds[3][q] * e3;
        const int dc = wid * 16 + ql;
        const float Ov = OLds[0][q][dc] * e0 + OLds[1][q][dc] * e1 +
                         OLds[2][q][dc] * e2 + OLds[3][q][dc] * e3;
        Y[((size_t)b * 2048 + q0 + q) * 1024 + h * 64 + dc] = f2bf(Ov / L);
    }
}

// ---------------- Hyperbolic residual: out = expmap(x, v, c), per-head wave ------
__global__ __launch_bounds__(256) void expmap_kernel(const float* __restrict__ x,
                                                     const float* __restrict__ v,
                                                     const float* __restrict__ carr,
                                                     float* __restrict__ out) {
    const int blk = blockIdx.x;
    const int row = blk >> 2;
    const int head = (blk & 3) * 4 + (threadIdx.x >> 6);
    const int lane = threadIdx.x & 63;
    const size_t idx = (size_t)row * 1024 + head * 64 + lane;
    float c = carr[head];
    c = fminf(fmaxf(c, 1e-4f), 1.0f);
    const float xe = x[idx], ve = v[idx];
    const float xn = wred(xe * xe);
    const float vns = wred(ve * ve);
    const float vn = sqrtf(vns + 1e-9f);
    const float sf = 2.0f / (1.0f + c * xn + 1e-9f);
    const float targ = fabsf(0.5f * c * sf * vns);
    const float coeff = (1.0f / (sqrtf(c + 1e-9f) + 1e-9f)) * tanhf(sqrtf(targ + 1e-9f));
    const float ye = coeff * ve / (vn + 1e-9f);
    const float yn = wred(ye * ye);
    const float ip = wred(xe * ye);
    const float num = (1.0f + 2.0f * c * ip + c * yn) * xe + (1.0f - c * xn) * ye;
    const float den = 1.0f + 2.0f * c * ip + c * c * xn * yn;
    out[idx] = num / (den + 1e-9f);
}

extern "C" void kernel_launch(void* const* d_in, const int* in_sizes, int n_in,
                              void* d_out, int out_size, void* d_ws, size_t ws_size,
                              hipStream_t stream) {
    (void)in_sizes; (void)n_in; (void)out_size; (void)ws_size;
    const float* x      = (const float*)d_in[0];
    const float* ln1_g  = (const float*)d_in[1];
    const float* w_qkv  = (const float*)d_in[2];
    const float* w_proj = (const float*)d_in[3];
    const float* c_attn = (const float*)d_in[4];
    const float* ln2_g  = (const float*)d_in[5];
    const float* w_fc   = (const float*)d_in[6];
    const float* w_mlp  = (const float*)d_in[7];
    const float* c_mlp  = (const float*)d_in[8];
    float* out = (float*)d_out;
    char* ws = (char*)d_ws;
    const size_t MB = 1024 * 1024;

    short* wqkv_bf  = (short*)(ws + 0 * MB);    // 6 MB
    short* wproj_bf = (short*)(ws + 6 * MB);    // 2 MB
    short* wfc_bf   = (short*)(ws + 8 * MB);    // 8 MB
    short* wmlp_bf  = (short*)(ws + 16 * MB);   // 8 MB
    short* y_bf     = (short*)(ws + 24 * MB);   // 8 MB (LN1 out; reused for LN2 out)
    short* q_bf     = (short*)(ws + 32 * MB);   // 8 MB
    short* k_bf     = (short*)(ws + 40 * MB);   // 8 MB
    short* vT_bf    = (short*)(ws + 48 * MB);   // 8 MB
    short* att_bf   = (short*)(ws + 56 * MB);   // 8 MB
    float* a_f32    = (float*)(ws + 64 * MB);   // 16 MB
    float* x1       = (float*)(ws + 80 * MB);   // 16 MB
    short* g_bf     = (short*)(ws + 32 * MB);   // 32 MB (reuses q/k/vT/att)
    float* h_f32    = (float*)(ws + 64 * MB);   // 16 MB (reuses a)

    cvt_kernel<<<3072, 256, 0, stream>>>(w_qkv, wqkv_bf, 3072 * 1024 / 4);
    cvt_kernel<<<1024, 256, 0, stream>>>(w_proj, wproj_bf, 1024 * 1024 / 4);
    cvt_kernel<<<4096, 256, 0, stream>>>(w_fc, wfc_bf, 4096 * 1024 / 4);
    cvt_kernel<<<4096, 256, 0, stream>>>(w_mlp, wmlp_bf, 1024 * 4096 / 4);

    ln_kernel<<<4096, 256, 0, stream>>>(x, ln1_g, y_bf);
    gemm_bt<0><<<dim3(32, 24), 256, 0, stream>>>(y_bf, wqkv_bf, 4096, 3072, 1024,
                                                 q_bf, k_bf, vT_bf);
    attn_kernel<<<dim3(128, 32), 256, 0, stream>>>(q_bf, k_bf, vT_bf, att_bf);
    gemm_bt<1><<<dim3(32, 8), 256, 0, stream>>>(att_bf, wproj_bf, 4096, 1024, 1024,
                                                a_f32, nullptr, nullptr);
    expmap_kernel<<<16384, 256, 0, stream>>>(x, a_f32, c_attn, x1);
    ln_kernel<<<4096, 256, 0, stream>>>(x1, ln2_g, y_bf);
    gemm_bt<2><<<dim3(32, 32), 256, 0, stream>>>(y_bf, wfc_bf, 4096, 4096, 1024,
                                                 g_bf, nullptr, nullptr);
    gemm_bt<1><<<dim3(32, 8), 256, 0, stream>>>(g_bf, wmlp_bf, 4096, 1024, 4096,
                                                h_f32, nullptr, nullptr);
    expmap_kernel<<<16384, 256, 0, stream>>>(x1, h_f32, c_mlp, out);
}